// Round 1
// baseline (456.143 us; speedup 1.0000x reference)
//
#include <hip/hip_runtime.h>
#include <hip/hip_bf16.h>

#define N_NODES 8192
#define IN_DIM  256
#define H_DIM   128
#define N_EDGES 262144

typedef __attribute__((ext_vector_type(8))) short bf16x8;
typedef __attribute__((ext_vector_type(4))) float f32x4;

// ---------- degree + CSR build ----------
__global__ void hist_kernel(const int* __restrict__ src, const int* __restrict__ dst,
                            int* __restrict__ degc, int* __restrict__ dstc) {
    int e = blockIdx.x * 256 + threadIdx.x;
    if (e < N_EDGES) {
        atomicAdd(&degc[src[e]], 1);   // deg = count of src occurrences (+1 self-loop later)
        atomicAdd(&dstc[dst[e]], 1);   // CSR row sizes keyed by dst
    }
}

__global__ void dinv_kernel(const int* __restrict__ degc, float* __restrict__ dinv) {
    int n = blockIdx.x * 256 + threadIdx.x;
    if (n < N_NODES) dinv[n] = 1.0f / sqrtf((float)(degc[n] + 1));  // +1 self loop; always >=1
}

__global__ void scan_kernel(const int* __restrict__ cnt, int* __restrict__ rowptr,
                            int* __restrict__ cursor) {
    __shared__ int partial[256];
    int tid = threadIdx.x;
    const int chunk = N_NODES / 256;   // 32
    int base = tid * chunk;
    int s = 0;
    for (int i = 0; i < chunk; ++i) s += cnt[base + i];
    partial[tid] = s;
    __syncthreads();
    if (tid == 0) {
        int run = 0;
        for (int i = 0; i < 256; ++i) { int v = partial[i]; partial[i] = run; run += v; }
        rowptr[N_NODES] = run;
    }
    __syncthreads();
    int run = partial[tid];
    for (int i = 0; i < chunk; ++i) {
        rowptr[base + i] = run;
        cursor[base + i] = run;
        run += cnt[base + i];
    }
}

__global__ void fill_kernel(const int* __restrict__ src, const int* __restrict__ dst,
                            int* __restrict__ cursor, int* __restrict__ colidx) {
    int e = blockIdx.x * 256 + threadIdx.x;
    if (e < N_EDGES) {
        int p = atomicAdd(&cursor[dst[e]], 1);
        colidx[p] = src[e];
    }
}

// ---------- h = leaky_relu(X @ W + b); also emits tmp0 = h * dinv ----------
__global__ __launch_bounds__(256) void gemm_h_kernel(const float* __restrict__ X,
                                                     const float* __restrict__ W,
                                                     const float* __restrict__ b,
                                                     const float* __restrict__ dinv,
                                                     float* __restrict__ F0,
                                                     float* __restrict__ tmp0) {
    __shared__ float xs[8][IN_DIM];
    int tid  = threadIdx.x;
    int col  = tid & 127;
    int half = tid >> 7;               // 0 or 1
    int row0 = blockIdx.x * 8;
    for (int i = tid; i < 8 * IN_DIM; i += 256)
        xs[i >> 8][i & 255] = X[(size_t)(row0 + (i >> 8)) * IN_DIM + (i & 255)];
    __syncthreads();
    float s0 = 0.f, s1 = 0.f, s2 = 0.f, s3 = 0.f;
    int r0 = half * 4;
    for (int k = 0; k < IN_DIM; ++k) {
        float wv = W[k * H_DIM + col];
        s0 += xs[r0 + 0][k] * wv;
        s1 += xs[r0 + 1][k] * wv;
        s2 += xs[r0 + 2][k] * wv;
        s3 += xs[r0 + 3][k] * wv;
    }
    float bb = b[col];
    float sv[4] = {s0, s1, s2, s3};
    for (int r = 0; r < 4; ++r) {
        int row = row0 + r0 + r;
        float v = sv[r] + bb;
        v = v > 0.f ? v : 0.01f * v;   // leaky_relu slope 0.01
        F0[(size_t)row * H_DIM + col]   = v;
        tmp0[(size_t)row * H_DIM + col] = v * dinv[row];
    }
}

// ---------- one propagation step (gather form) ----------
// Fout[n] = Fin[n] - dinv[n] * ( tmpin[n] + sum_{e: dst=n} tmpin[src_e] )
// tmpout[n] = Fout[n] * dinv[n]   (feeds the next step)
__global__ __launch_bounds__(128) void prop_kernel(const float* __restrict__ Fin,
                                                   const float* __restrict__ tmpin,
                                                   float* __restrict__ Fout,
                                                   float* __restrict__ tmpout,
                                                   const float* __restrict__ dinv,
                                                   const int* __restrict__ rowptr,
                                                   const int* __restrict__ colidx) {
    int n = blockIdx.x;
    int j = threadIdx.x;
    float dv  = dinv[n];
    float fs  = Fin[(size_t)n * H_DIM + j];
    float sum = tmpin[(size_t)n * H_DIM + j];   // self loop term
    int beg = rowptr[n], end = rowptr[n + 1];
    for (int e = beg; e < end; ++e) {
        int srcn = colidx[e];                    // wave-uniform
        sum += tmpin[(size_t)srcn * H_DIM + j];  // coalesced 512B row
    }
    float v = fs - sum * dv;
    Fout[(size_t)n * H_DIM + j]   = v;
    tmpout[(size_t)n * H_DIM + j] = v * dv;
}

// ---------- acc_t = sum_k theta[t][k] * F_k, cast to bf16 ----------
__global__ __launch_bounds__(256) void acc_kernel(const float* __restrict__ F0,
                                                  const float* __restrict__ F1,
                                                  const float* __restrict__ F2,
                                                  const float* __restrict__ F3,
                                                  __hip_bfloat16* __restrict__ accb) {
    int i = blockIdx.x * 256 + threadIdx.x;        // over N*H = 1M
    const size_t NH = (size_t)N_NODES * H_DIM;
    float f0 = F0[i], f1 = F1[i], f2 = F2[i], f3 = F3[i];
    accb[0 * NH + i] = __float2bfloat16(2.5f * f0 - 5.0f * f1 + 3.75f * f2 - 1.25f * f3);
    accb[1 * NH + i] = __float2bfloat16(           5.0f * f1 - 7.5f  * f2 + 3.75f * f3);
    accb[2 * NH + i] = __float2bfloat16(                       3.75f * f2 - 3.75f * f3);
    accb[3 * NH + i] = __float2bfloat16(                                    1.25f * f3);
}

// ---------- out_t = acc_t @ acc_t^T  (symmetric, bf16 MFMA, f32 out) ----------
__global__ __launch_bounds__(256) void out_gemm_kernel(const __hip_bfloat16* __restrict__ accb,
                                                       float* __restrict__ out) {
    int t = blockIdx.z;
    const short* A = (const short*)accb + (size_t)t * N_NODES * H_DIM;
    int lane = threadIdx.x & 63;
    int w    = threadIdx.x >> 6;       // 0..3
    int wr = w >> 1, wc = w & 1;       // 2x2 waves, 64x64 each
    int brow = blockIdx.x * 128 + wr * 64;
    int bcol = blockIdx.y * 128 + wc * 64;
    int r16 = lane & 15;               // fragment row/col within 16
    int kg  = lane >> 4;               // k-group 0..3

    f32x4 c[4][4] = {};
    for (int kk = 0; kk < 4; ++kk) {   // K = 128 in chunks of 32
        int koff = kk * 32 + kg * 8;
        bf16x8 a[4], bfr[4];
#pragma unroll
        for (int m = 0; m < 4; ++m)
            a[m] = *(const bf16x8*)(A + (size_t)(brow + m * 16 + r16) * H_DIM + koff);
#pragma unroll
        for (int n = 0; n < 4; ++n)
            bfr[n] = *(const bf16x8*)(A + (size_t)(bcol + n * 16 + r16) * H_DIM + koff);
#pragma unroll
        for (int m = 0; m < 4; ++m)
#pragma unroll
            for (int n = 0; n < 4; ++n)
                c[m][n] = __builtin_amdgcn_mfma_f32_16x16x32_bf16(a[m], bfr[n], c[m][n], 0, 0, 0);
    }

    float* O = out + (size_t)t * N_NODES * N_NODES;
#pragma unroll
    for (int m = 0; m < 4; ++m)
#pragma unroll
        for (int n = 0; n < 4; ++n)
#pragma unroll
            for (int r = 0; r < 4; ++r) {
                int row = brow + m * 16 + kg * 4 + r;   // C/D: row=(lane>>4)*4+reg
                int col = bcol + n * 16 + r16;          //       col=lane&15
                O[(size_t)row * N_NODES + col] = c[m][n][r];
            }
}

extern "C" void kernel_launch(void* const* d_in, const int* in_sizes, int n_in,
                              void* d_out, int out_size, void* d_ws, size_t ws_size,
                              hipStream_t stream) {
    const float* in_feat = (const float*)d_in[0];
    const float* W       = (const float*)d_in[1];
    const float* b       = (const float*)d_in[2];
    const int*   src     = (const int*)d_in[3];
    const int*   dst     = (const int*)d_in[4];
    float* out = (float*)d_out;

    char* ws = (char*)d_ws;
    const size_t NH4 = (size_t)N_NODES * H_DIM * sizeof(float);   // 4 MB
    float* F0 = (float*)(ws + 0 * NH4);
    float* F1 = (float*)(ws + 1 * NH4);
    float* F2 = (float*)(ws + 2 * NH4);
    float* F3 = (float*)(ws + 3 * NH4);
    float* tA = (float*)(ws + 4 * NH4);
    float* tB = (float*)(ws + 5 * NH4);
    __hip_bfloat16* accb = (__hip_bfloat16*)(ws + 6 * NH4);       // 4 * N*H * 2B = 8 MB
    char* p = ws + 8 * NH4;
    int*   degc   = (int*)p;   p += 32768;
    int*   dstc   = (int*)p;   p += 32768;
    float* dinv   = (float*)p; p += 32768;
    int*   rowptr = (int*)p;   p += 33792;   // N+1 ints, padded
    int*   cursor = (int*)p;   p += 32768;
    int*   colidx = (int*)p;                  // E ints = 1 MB

    hipMemsetAsync(degc, 0, 32768, stream);
    hipMemsetAsync(dstc, 0, 32768, stream);

    hist_kernel<<<N_EDGES / 256, 256, 0, stream>>>(src, dst, degc, dstc);
    dinv_kernel<<<N_NODES / 256, 256, 0, stream>>>(degc, dinv);
    scan_kernel<<<1, 256, 0, stream>>>(dstc, rowptr, cursor);
    fill_kernel<<<N_EDGES / 256, 256, 0, stream>>>(src, dst, cursor, colidx);

    gemm_h_kernel<<<N_NODES / 8, 256, 0, stream>>>(in_feat, W, b, dinv, F0, tA);

    prop_kernel<<<N_NODES, 128, 0, stream>>>(F0, tA, F1, tB, dinv, rowptr, colidx);
    prop_kernel<<<N_NODES, 128, 0, stream>>>(F1, tB, F2, tA, dinv, rowptr, colidx);
    prop_kernel<<<N_NODES, 128, 0, stream>>>(F2, tA, F3, tB, dinv, rowptr, colidx);

    acc_kernel<<<(N_NODES * H_DIM) / 256, 256, 0, stream>>>(F0, F1, F2, F3, accb);

    dim3 g(N_NODES / 128, N_NODES / 128, 4);
    out_gemm_kernel<<<g, 256, 0, stream>>>(accb, out);
}

// Round 2
// 445.525 us; speedup vs baseline: 1.0238x; 1.0238x over previous
//
#include <hip/hip_runtime.h>
#include <hip/hip_bf16.h>

#define N_NODES 8192
#define IN_DIM  256
#define H_DIM   128
#define N_EDGES 262144

typedef __attribute__((ext_vector_type(8))) short bf16x8;
typedef __attribute__((ext_vector_type(4))) float f32x4;
typedef __attribute__((ext_vector_type(4))) short s16x4;

static __device__ inline short bf16_hi(float x) {
    __hip_bfloat16 h = __float2bfloat16(x);
    return *(short*)&h;
}
static __device__ inline float bf16_val(short s) {
    __hip_bfloat16 h = *(__hip_bfloat16*)&s;
    return __bfloat162float(h);
}

// ---------- degree + CSR build ----------
__global__ void hist_kernel(const int* __restrict__ src, const int* __restrict__ dst,
                            int* __restrict__ degc, int* __restrict__ dstc) {
    int e = blockIdx.x * 256 + threadIdx.x;
    if (e < N_EDGES) {
        atomicAdd(&degc[src[e]], 1);
        atomicAdd(&dstc[dst[e]], 1);
    }
}

__global__ void dinv_kernel(const int* __restrict__ degc, float* __restrict__ dinv) {
    int n = blockIdx.x * 256 + threadIdx.x;
    if (n < N_NODES) dinv[n] = 1.0f / sqrtf((float)(degc[n] + 1));
}

__global__ void scan_kernel(const int* __restrict__ cnt, int* __restrict__ rowptr,
                            int* __restrict__ cursor) {
    __shared__ int buf[2][256];
    int tid = threadIdx.x;
    const int chunk = N_NODES / 256;   // 32
    int base = tid * chunk;
    int s = 0;
    for (int i = 0; i < chunk; ++i) s += cnt[base + i];
    buf[0][tid] = s;
    __syncthreads();
    int pp = 0;
    for (int off = 1; off < 256; off <<= 1) {
        buf[pp ^ 1][tid] = buf[pp][tid] + (tid >= off ? buf[pp][tid - off] : 0);
        pp ^= 1;
        __syncthreads();
    }
    if (tid == 255) rowptr[N_NODES] = buf[pp][255];
    int run = buf[pp][tid] - s;        // exclusive prefix of per-thread partials
    for (int i = 0; i < chunk; ++i) {
        rowptr[base + i] = run;
        cursor[base + i] = run;
        run += cnt[base + i];
    }
}

__global__ void fill_kernel(const int* __restrict__ src, const int* __restrict__ dst,
                            int* __restrict__ cursor, int* __restrict__ colidx) {
    int e = blockIdx.x * 256 + threadIdx.x;
    if (e < N_EDGES) {
        int p = atomicAdd(&cursor[dst[e]], 1);
        colidx[p] = src[e];
    }
}

// ---------- split X (f32) into bf16 hi/lo ----------
__global__ __launch_bounds__(256) void cvtX_kernel(const f32x4* __restrict__ X,
                                                   s16x4* __restrict__ Xhi,
                                                   s16x4* __restrict__ Xlo) {
    int i = blockIdx.x * 256 + threadIdx.x;   // over N*IN/4 = 524288
    f32x4 x = X[i];
    s16x4 hi, lo;
#pragma unroll
    for (int j = 0; j < 4; ++j) {
        short h = bf16_hi(x[j]);
        hi[j] = h;
        lo[j] = bf16_hi(x[j] - bf16_val(h));
    }
    Xhi[i] = hi;
    Xlo[i] = lo;
}

// ---------- W^T split into bf16 hi/lo:  Wt[j][k] = W[k][j] ----------
__global__ __launch_bounds__(256) void cvtW_kernel(const float* __restrict__ W,
                                                   short* __restrict__ Wthi,
                                                   short* __restrict__ Wtlo) {
    int t = blockIdx.x * 256 + threadIdx.x;   // over 128*256 = 32768, k fastest
    int k = t & 255, j = t >> 8;
    float w = W[k * H_DIM + j];
    short h = bf16_hi(w);
    Wthi[t] = h;
    Wtlo[t] = bf16_hi(w - bf16_val(h));
}

// ---------- h = leaky_relu(X @ W + b) via split-bf16 MFMA; emits F0 and tmp0=h*dinv ----------
__global__ __launch_bounds__(256) void gemm_h_mfma(const short* __restrict__ Xhi,
                                                   const short* __restrict__ Xlo,
                                                   const short* __restrict__ Wthi,
                                                   const short* __restrict__ Wtlo,
                                                   const float* __restrict__ b,
                                                   const float* __restrict__ dinv,
                                                   float* __restrict__ F0,
                                                   float* __restrict__ tmp0) {
    int lane = threadIdx.x & 63;
    int w    = threadIdx.x >> 6;
    int wr = w >> 1, wc = w & 1;          // 2x2 waves, 64x64 each
    int brow = blockIdx.x * 128 + wr * 64;
    int bcol = wc * 64;
    int r16 = lane & 15;
    int kg  = lane >> 4;

    f32x4 c[4][4] = {};
    for (int kk = 0; kk < IN_DIM / 32; ++kk) {   // 8
        int koff = kk * 32 + kg * 8;
        bf16x8 ah[4], al[4], bh[4], bl[4];
#pragma unroll
        for (int m = 0; m < 4; ++m) {
            size_t off = (size_t)(brow + m * 16 + r16) * IN_DIM + koff;
            ah[m] = *(const bf16x8*)(Xhi + off);
            al[m] = *(const bf16x8*)(Xlo + off);
        }
#pragma unroll
        for (int n = 0; n < 4; ++n) {
            size_t off = (size_t)(bcol + n * 16 + r16) * IN_DIM + koff;
            bh[n] = *(const bf16x8*)(Wthi + off);
            bl[n] = *(const bf16x8*)(Wtlo + off);
        }
#pragma unroll
        for (int m = 0; m < 4; ++m)
#pragma unroll
            for (int n = 0; n < 4; ++n) {
                c[m][n] = __builtin_amdgcn_mfma_f32_16x16x32_bf16(ah[m], bh[n], c[m][n], 0, 0, 0);
                c[m][n] = __builtin_amdgcn_mfma_f32_16x16x32_bf16(ah[m], bl[n], c[m][n], 0, 0, 0);
                c[m][n] = __builtin_amdgcn_mfma_f32_16x16x32_bf16(al[m], bh[n], c[m][n], 0, 0, 0);
            }
    }
#pragma unroll
    for (int m = 0; m < 4; ++m)
#pragma unroll
        for (int n = 0; n < 4; ++n)
#pragma unroll
            for (int r = 0; r < 4; ++r) {
                int row = brow + m * 16 + kg * 4 + r;   // C/D: row=(lane>>4)*4+reg
                int col = bcol + n * 16 + r16;          //      col=lane&15
                float v = c[m][n][r] + b[col];
                v = v > 0.f ? v : 0.01f * v;
                F0[(size_t)row * H_DIM + col]   = v;
                tmp0[(size_t)row * H_DIM + col] = v * dinv[row];
            }
}

// ---------- one propagation step (gather form, 4-wide unrolled) ----------
__global__ __launch_bounds__(128) void prop_kernel(const float* __restrict__ Fin,
                                                   const float* __restrict__ tmpin,
                                                   float* __restrict__ Fout,
                                                   float* __restrict__ tmpout,
                                                   const float* __restrict__ dinv,
                                                   const int* __restrict__ rowptr,
                                                   const int* __restrict__ colidx) {
    int n = blockIdx.x;
    int j = threadIdx.x;
    float dv  = dinv[n];
    float fs  = Fin[(size_t)n * H_DIM + j];
    float sum = tmpin[(size_t)n * H_DIM + j];   // self loop
    int beg = rowptr[n], end = rowptr[n + 1];
    int e = beg;
    for (; e + 4 <= end; e += 4) {
        int s0 = colidx[e], s1 = colidx[e + 1], s2 = colidx[e + 2], s3 = colidx[e + 3];
        float v0 = tmpin[(size_t)s0 * H_DIM + j];
        float v1 = tmpin[(size_t)s1 * H_DIM + j];
        float v2 = tmpin[(size_t)s2 * H_DIM + j];
        float v3 = tmpin[(size_t)s3 * H_DIM + j];
        sum += v0 + v1 + v2 + v3;
    }
    for (; e < end; ++e)
        sum += tmpin[(size_t)colidx[e] * H_DIM + j];
    float v = fs - sum * dv;
    Fout[(size_t)n * H_DIM + j]   = v;
    tmpout[(size_t)n * H_DIM + j] = v * dv;
}

// ---------- acc_t = sum_k theta[t][k] * F_k, vectorized, cast to bf16 ----------
__global__ __launch_bounds__(256) void acc_kernel(const f32x4* __restrict__ F0,
                                                  const f32x4* __restrict__ F1,
                                                  const f32x4* __restrict__ F2,
                                                  const f32x4* __restrict__ F3,
                                                  s16x4* __restrict__ accb) {
    int i = blockIdx.x * 256 + threadIdx.x;        // over N*H/4 = 262144
    const size_t NH4 = (size_t)N_NODES * H_DIM / 4;
    f32x4 f0 = F0[i], f1 = F1[i], f2 = F2[i], f3 = F3[i];
    f32x4 a0 = 2.5f * f0 - 5.0f * f1 + 3.75f * f2 - 1.25f * f3;
    f32x4 a1 =           5.0f * f1 - 7.5f  * f2 + 3.75f * f3;
    f32x4 a2 =                      3.75f * f2 - 3.75f * f3;
    f32x4 a3 =                                   1.25f * f3;
    s16x4 o0, o1, o2, o3;
#pragma unroll
    for (int j = 0; j < 4; ++j) {
        o0[j] = bf16_hi(a0[j]); o1[j] = bf16_hi(a1[j]);
        o2[j] = bf16_hi(a2[j]); o3[j] = bf16_hi(a3[j]);
    }
    accb[0 * NH4 + i] = o0;
    accb[1 * NH4 + i] = o1;
    accb[2 * NH4 + i] = o2;
    accb[3 * NH4 + i] = o3;
}

// ---------- out_t = acc_t @ acc_t^T  (symmetric; transposed f32x4 stores) ----------
__global__ __launch_bounds__(256) void out_gemm_kernel(const short* __restrict__ accb,
                                                       float* __restrict__ out) {
    int t = blockIdx.z;
    const short* A = accb + (size_t)t * N_NODES * H_DIM;
    int lane = threadIdx.x & 63;
    int w    = threadIdx.x >> 6;
    int wr = w >> 1, wc = w & 1;       // 2x2 waves, 64x64 each
    int brow = blockIdx.x * 128 + wr * 64;
    int bcol = blockIdx.y * 128 + wc * 64;
    int r16 = lane & 15;
    int kg  = lane >> 4;

    f32x4 c[4][4] = {};
    for (int kk = 0; kk < 4; ++kk) {   // K = 128 in chunks of 32
        int koff = kk * 32 + kg * 8;
        bf16x8 a[4], bfr[4];
#pragma unroll
        for (int m = 0; m < 4; ++m)
            a[m] = *(const bf16x8*)(A + (size_t)(brow + m * 16 + r16) * H_DIM + koff);
#pragma unroll
        for (int n = 0; n < 4; ++n)
            bfr[n] = *(const bf16x8*)(A + (size_t)(bcol + n * 16 + r16) * H_DIM + koff);
#pragma unroll
        for (int m = 0; m < 4; ++m)
#pragma unroll
            for (int n = 0; n < 4; ++n)
                c[m][n] = __builtin_amdgcn_mfma_f32_16x16x32_bf16(a[m], bfr[n], c[m][n], 0, 0, 0);
    }

    // Output is exactly symmetric (same products, same k-reduction order), so we
    // may store each fragment at the transposed location, where the 4 accumulator
    // regs (consecutive rows) become 4 consecutive floats -> global_store_dwordx4.
    float* O = out + (size_t)t * N_NODES * N_NODES;
#pragma unroll
    for (int m = 0; m < 4; ++m)
#pragma unroll
        for (int n = 0; n < 4; ++n) {
            int col  = bcol + n * 16 + r16;
            int row0 = brow + m * 16 + kg * 4;
            *(f32x4*)(O + (size_t)col * N_NODES + row0) = c[m][n];
        }
}

extern "C" void kernel_launch(void* const* d_in, const int* in_sizes, int n_in,
                              void* d_out, int out_size, void* d_ws, size_t ws_size,
                              hipStream_t stream) {
    const float* in_feat = (const float*)d_in[0];
    const float* W       = (const float*)d_in[1];
    const float* b       = (const float*)d_in[2];
    const int*   src     = (const int*)d_in[3];
    const int*   dst     = (const int*)d_in[4];
    float* out = (float*)d_out;

    char* ws = (char*)d_ws;
    const size_t NH4 = (size_t)N_NODES * H_DIM * sizeof(float);   // 4 MB
    float* F0 = (float*)(ws + 0 * NH4);
    float* F1 = (float*)(ws + 1 * NH4);
    float* F2 = (float*)(ws + 2 * NH4);
    float* F3 = (float*)(ws + 3 * NH4);
    float* tA = (float*)(ws + 4 * NH4);
    float* tB = (float*)(ws + 5 * NH4);
    char*  accb_region = ws + 6 * NH4;                            // 8 MB
    short* accb = (short*)accb_region;
    // Xhi/Xlo overlay the accb region (dead until acc_kernel, which runs after gemm+props)
    short* Xhi = (short*)accb_region;                             // 4 MB
    short* Xlo = (short*)(accb_region + NH4);                     // 4 MB
    char* p = ws + 8 * NH4;
    int*   degc   = (int*)p;   p += 32768;
    int*   dstc   = (int*)p;   p += 32768;
    float* dinv   = (float*)p; p += 32768;
    int*   rowptr = (int*)p;   p += 33792;   // N+1 ints, padded
    int*   cursor = (int*)p;   p += 32768;
    int*   colidx = (int*)p;   p += (size_t)N_EDGES * 4;          // 1 MB
    short* Wthi   = (short*)p; p += 65536;   // 128x256 bf16
    short* Wtlo   = (short*)p;

    hipMemsetAsync(degc, 0, 32768, stream);
    hipMemsetAsync(dstc, 0, 32768, stream);

    hist_kernel<<<N_EDGES / 256, 256, 0, stream>>>(src, dst, degc, dstc);
    dinv_kernel<<<N_NODES / 256, 256, 0, stream>>>(degc, dinv);
    scan_kernel<<<1, 256, 0, stream>>>(dstc, rowptr, cursor);
    fill_kernel<<<N_EDGES / 256, 256, 0, stream>>>(src, dst, cursor, colidx);

    cvtX_kernel<<<(N_NODES * IN_DIM / 4) / 256, 256, 0, stream>>>((const f32x4*)in_feat,
                                                                  (s16x4*)Xhi, (s16x4*)Xlo);
    cvtW_kernel<<<(H_DIM * IN_DIM) / 256, 256, 0, stream>>>(W, Wthi, Wtlo);

    gemm_h_mfma<<<N_NODES / 128, 256, 0, stream>>>(Xhi, Xlo, Wthi, Wtlo, b, dinv, F0, tA);

    prop_kernel<<<N_NODES, 128, 0, stream>>>(F0, tA, F1, tB, dinv, rowptr, colidx);
    prop_kernel<<<N_NODES, 128, 0, stream>>>(F1, tB, F2, tA, dinv, rowptr, colidx);
    prop_kernel<<<N_NODES, 128, 0, stream>>>(F2, tA, F3, tB, dinv, rowptr, colidx);

    acc_kernel<<<(N_NODES * H_DIM / 4) / 256, 256, 0, stream>>>((const f32x4*)F0, (const f32x4*)F1,
                                                                (const f32x4*)F2, (const f32x4*)F3,
                                                                (s16x4*)accb);

    dim3 g(N_NODES / 128, N_NODES / 128, 4);
    out_gemm_kernel<<<g, 256, 0, stream>>>(accb, out);
}

// Round 3
// 433.743 us; speedup vs baseline: 1.0516x; 1.0272x over previous
//
#include <hip/hip_runtime.h>
#include <hip/hip_bf16.h>

#define N_NODES 8192
#define IN_DIM  256
#define H_DIM   128
#define N_EDGES 262144

typedef __attribute__((ext_vector_type(8))) short bf16x8;
typedef __attribute__((ext_vector_type(4))) float f32x4;
typedef __attribute__((ext_vector_type(4))) short s16x4;

static __device__ inline short bf16_hi(float x) {
    __hip_bfloat16 h = __float2bfloat16(x);
    return *(short*)&h;
}
static __device__ inline float bf16_val(short s) {
    __hip_bfloat16 h = *(__hip_bfloat16*)&s;
    return __bfloat162float(h);
}

// ---------- degree + CSR build ----------
__global__ void hist_kernel(const int* __restrict__ src, const int* __restrict__ dst,
                            int* __restrict__ degc, int* __restrict__ dstc) {
    int e = blockIdx.x * 256 + threadIdx.x;
    if (e < N_EDGES) {
        atomicAdd(&degc[src[e]], 1);
        atomicAdd(&dstc[dst[e]], 1);
    }
}

__global__ void dinv_kernel(const int* __restrict__ degc, float* __restrict__ dinv) {
    int n = blockIdx.x * 256 + threadIdx.x;
    if (n < N_NODES) dinv[n] = 1.0f / sqrtf((float)(degc[n] + 1));
}

__global__ void scan_kernel(const int* __restrict__ cnt, int* __restrict__ rowptr,
                            int* __restrict__ cursor) {
    __shared__ int buf[2][256];
    int tid = threadIdx.x;
    const int chunk = N_NODES / 256;   // 32
    int base = tid * chunk;
    int s = 0;
    for (int i = 0; i < chunk; ++i) s += cnt[base + i];
    buf[0][tid] = s;
    __syncthreads();
    int pp = 0;
    for (int off = 1; off < 256; off <<= 1) {
        buf[pp ^ 1][tid] = buf[pp][tid] + (tid >= off ? buf[pp][tid - off] : 0);
        pp ^= 1;
        __syncthreads();
    }
    if (tid == 255) rowptr[N_NODES] = buf[pp][255];
    int run = buf[pp][tid] - s;        // exclusive prefix of per-thread partials
    for (int i = 0; i < chunk; ++i) {
        rowptr[base + i] = run;
        cursor[base + i] = run;
        run += cnt[base + i];
    }
}

__global__ void fill_kernel(const int* __restrict__ src, const int* __restrict__ dst,
                            int* __restrict__ cursor, int* __restrict__ colidx) {
    int e = blockIdx.x * 256 + threadIdx.x;
    if (e < N_EDGES) {
        int p = atomicAdd(&cursor[dst[e]], 1);
        colidx[p] = src[e];
    }
}

// ---------- split X (f32) into bf16 hi/lo ----------
__global__ __launch_bounds__(256) void cvtX_kernel(const f32x4* __restrict__ X,
                                                   s16x4* __restrict__ Xhi,
                                                   s16x4* __restrict__ Xlo) {
    int i = blockIdx.x * 256 + threadIdx.x;   // over N*IN/4 = 524288
    f32x4 x = X[i];
    s16x4 hi, lo;
#pragma unroll
    for (int j = 0; j < 4; ++j) {
        short h = bf16_hi(x[j]);
        hi[j] = h;
        lo[j] = bf16_hi(x[j] - bf16_val(h));
    }
    Xhi[i] = hi;
    Xlo[i] = lo;
}

// ---------- W^T split into bf16 hi/lo:  Wt[j][k] = W[k][j] ----------
__global__ __launch_bounds__(256) void cvtW_kernel(const float* __restrict__ W,
                                                   short* __restrict__ Wthi,
                                                   short* __restrict__ Wtlo) {
    int t = blockIdx.x * 256 + threadIdx.x;   // over 128*256 = 32768, k fastest
    int k = t & 255, j = t >> 8;
    float w = W[k * H_DIM + j];
    short h = bf16_hi(w);
    Wthi[t] = h;
    Wtlo[t] = bf16_hi(w - bf16_val(h));
}

// ---------- h = leaky_relu(X @ W + b) via split-bf16 MFMA; emits F0 and tmp0=h*dinv ----------
__global__ __launch_bounds__(256) void gemm_h_mfma(const short* __restrict__ Xhi,
                                                   const short* __restrict__ Xlo,
                                                   const short* __restrict__ Wthi,
                                                   const short* __restrict__ Wtlo,
                                                   const float* __restrict__ b,
                                                   const float* __restrict__ dinv,
                                                   float* __restrict__ F0,
                                                   float* __restrict__ tmp0) {
    int lane = threadIdx.x & 63;
    int w    = threadIdx.x >> 6;
    int wr = w >> 1, wc = w & 1;          // 2x2 waves, 64x64 each
    int brow = blockIdx.x * 128 + wr * 64;
    int bcol = wc * 64;
    int r16 = lane & 15;
    int kg  = lane >> 4;

    f32x4 c[4][4] = {};
    for (int kk = 0; kk < IN_DIM / 32; ++kk) {   // 8
        int koff = kk * 32 + kg * 8;
        bf16x8 ah[4], al[4], bh[4], bl[4];
#pragma unroll
        for (int m = 0; m < 4; ++m) {
            size_t off = (size_t)(brow + m * 16 + r16) * IN_DIM + koff;
            ah[m] = *(const bf16x8*)(Xhi + off);
            al[m] = *(const bf16x8*)(Xlo + off);
        }
#pragma unroll
        for (int n = 0; n < 4; ++n) {
            size_t off = (size_t)(bcol + n * 16 + r16) * IN_DIM + koff;
            bh[n] = *(const bf16x8*)(Wthi + off);
            bl[n] = *(const bf16x8*)(Wtlo + off);
        }
#pragma unroll
        for (int m = 0; m < 4; ++m)
#pragma unroll
            for (int n = 0; n < 4; ++n) {
                c[m][n] = __builtin_amdgcn_mfma_f32_16x16x32_bf16(ah[m], bh[n], c[m][n], 0, 0, 0);
                c[m][n] = __builtin_amdgcn_mfma_f32_16x16x32_bf16(ah[m], bl[n], c[m][n], 0, 0, 0);
                c[m][n] = __builtin_amdgcn_mfma_f32_16x16x32_bf16(al[m], bh[n], c[m][n], 0, 0, 0);
            }
    }
#pragma unroll
    for (int m = 0; m < 4; ++m)
#pragma unroll
        for (int n = 0; n < 4; ++n)
#pragma unroll
            for (int r = 0; r < 4; ++r) {
                int row = brow + m * 16 + kg * 4 + r;   // C/D: row=(lane>>4)*4+reg
                int col = bcol + n * 16 + r16;          //      col=lane&15
                float v = c[m][n][r] + b[col];
                v = v > 0.f ? v : 0.01f * v;
                F0[(size_t)row * H_DIM + col]   = v;
                tmp0[(size_t)row * H_DIM + col] = v * dinv[row];
            }
}

// ---------- one propagation step (gather form, 4-wide unrolled) ----------
__global__ __launch_bounds__(128) void prop_kernel(const float* __restrict__ Fin,
                                                   const float* __restrict__ tmpin,
                                                   float* __restrict__ Fout,
                                                   float* __restrict__ tmpout,
                                                   const float* __restrict__ dinv,
                                                   const int* __restrict__ rowptr,
                                                   const int* __restrict__ colidx) {
    int n = blockIdx.x;
    int j = threadIdx.x;
    float dv  = dinv[n];
    float fs  = Fin[(size_t)n * H_DIM + j];
    float sum = tmpin[(size_t)n * H_DIM + j];   // self loop
    int beg = rowptr[n], end = rowptr[n + 1];
    int e = beg;
    for (; e + 4 <= end; e += 4) {
        int s0 = colidx[e], s1 = colidx[e + 1], s2 = colidx[e + 2], s3 = colidx[e + 3];
        float v0 = tmpin[(size_t)s0 * H_DIM + j];
        float v1 = tmpin[(size_t)s1 * H_DIM + j];
        float v2 = tmpin[(size_t)s2 * H_DIM + j];
        float v3 = tmpin[(size_t)s3 * H_DIM + j];
        sum += v0 + v1 + v2 + v3;
    }
    for (; e < end; ++e)
        sum += tmpin[(size_t)colidx[e] * H_DIM + j];
    float v = fs - sum * dv;
    Fout[(size_t)n * H_DIM + j]   = v;
    tmpout[(size_t)n * H_DIM + j] = v * dv;
}

// ---------- acc_t = sum_k theta[t][k] * F_k, vectorized, cast to bf16 ----------
__global__ __launch_bounds__(256) void acc_kernel(const f32x4* __restrict__ F0,
                                                  const f32x4* __restrict__ F1,
                                                  const f32x4* __restrict__ F2,
                                                  const f32x4* __restrict__ F3,
                                                  s16x4* __restrict__ accb) {
    int i = blockIdx.x * 256 + threadIdx.x;        // over N*H/4 = 262144
    const size_t NH4 = (size_t)N_NODES * H_DIM / 4;
    f32x4 f0 = F0[i], f1 = F1[i], f2 = F2[i], f3 = F3[i];
    f32x4 a0 = 2.5f * f0 - 5.0f * f1 + 3.75f * f2 - 1.25f * f3;
    f32x4 a1 =           5.0f * f1 - 7.5f  * f2 + 3.75f * f3;
    f32x4 a2 =                      3.75f * f2 - 3.75f * f3;
    f32x4 a3 =                                   1.25f * f3;
    s16x4 o0, o1, o2, o3;
#pragma unroll
    for (int j = 0; j < 4; ++j) {
        o0[j] = bf16_hi(a0[j]); o1[j] = bf16_hi(a1[j]);
        o2[j] = bf16_hi(a2[j]); o3[j] = bf16_hi(a3[j]);
    }
    accb[0 * NH4 + i] = o0;
    accb[1 * NH4 + i] = o1;
    accb[2 * NH4 + i] = o2;
    accb[3 * NH4 + i] = o3;
}

// ---------- out_t = acc_t @ acc_t^T  (symmetric; transposed nontemporal f32x4 stores) ----------
__global__ __launch_bounds__(256) void out_gemm_kernel(const short* __restrict__ accb,
                                                       float* __restrict__ out) {
    int t = blockIdx.z;
    const short* A = accb + (size_t)t * N_NODES * H_DIM;
    int lane = threadIdx.x & 63;
    int w    = threadIdx.x >> 6;
    int wr = w >> 1, wc = w & 1;       // 2x2 waves, 64x64 each
    int brow = blockIdx.x * 128 + wr * 64;
    int bcol = blockIdx.y * 128 + wc * 64;
    int r16 = lane & 15;
    int kg  = lane >> 4;

    f32x4 c[4][4] = {};
    for (int kk = 0; kk < 4; ++kk) {   // K = 128 in chunks of 32
        int koff = kk * 32 + kg * 8;
        bf16x8 a[4], bfr[4];
#pragma unroll
        for (int m = 0; m < 4; ++m)
            a[m] = *(const bf16x8*)(A + (size_t)(brow + m * 16 + r16) * H_DIM + koff);
#pragma unroll
        for (int n = 0; n < 4; ++n)
            bfr[n] = *(const bf16x8*)(A + (size_t)(bcol + n * 16 + r16) * H_DIM + koff);
#pragma unroll
        for (int m = 0; m < 4; ++m)
#pragma unroll
            for (int n = 0; n < 4; ++n)
                c[m][n] = __builtin_amdgcn_mfma_f32_16x16x32_bf16(a[m], bfr[n], c[m][n], 0, 0, 0);
    }

    // Output is exactly symmetric, so store each fragment transposed -> the 4
    // accumulator regs become 4 consecutive floats (global_store_dwordx4).
    // Non-temporal: keep the 1.07 GB write stream from evicting acc from L2.
    float* O = out + (size_t)t * N_NODES * N_NODES;
#pragma unroll
    for (int m = 0; m < 4; ++m)
#pragma unroll
        for (int n = 0; n < 4; ++n) {
            int col  = bcol + n * 16 + r16;
            int row0 = brow + m * 16 + kg * 4;
            __builtin_nontemporal_store(c[m][n], (f32x4*)(O + (size_t)col * N_NODES + row0));
        }
}

extern "C" void kernel_launch(void* const* d_in, const int* in_sizes, int n_in,
                              void* d_out, int out_size, void* d_ws, size_t ws_size,
                              hipStream_t stream) {
    const float* in_feat = (const float*)d_in[0];
    const float* W       = (const float*)d_in[1];
    const float* b       = (const float*)d_in[2];
    const int*   src     = (const int*)d_in[3];
    const int*   dst     = (const int*)d_in[4];
    float* out = (float*)d_out;

    char* ws = (char*)d_ws;
    const size_t NH4 = (size_t)N_NODES * H_DIM * sizeof(float);   // 4 MB
    float* F0 = (float*)(ws + 0 * NH4);
    float* F1 = (float*)(ws + 1 * NH4);
    float* F2 = (float*)(ws + 2 * NH4);
    float* F3 = (float*)(ws + 3 * NH4);
    float* tA = (float*)(ws + 4 * NH4);
    float* tB = (float*)(ws + 5 * NH4);
    char*  accb_region = ws + 6 * NH4;                            // 8 MB
    short* accb = (short*)accb_region;
    // Xhi/Xlo overlay the accb region (dead until acc_kernel, which runs after gemm+props)
    short* Xhi = (short*)accb_region;                             // 4 MB
    short* Xlo = (short*)(accb_region + NH4);                     // 4 MB
    char* p = ws + 8 * NH4;
    int*   degc   = (int*)p;   p += 32768;
    int*   dstc   = (int*)p;   p += 32768;
    float* dinv   = (float*)p; p += 32768;
    int*   rowptr = (int*)p;   p += 33792;   // N+1 ints, padded
    int*   cursor = (int*)p;   p += 32768;
    int*   colidx = (int*)p;   p += (size_t)N_EDGES * 4;          // 1 MB
    short* Wthi   = (short*)p; p += 65536;   // 128x256 bf16
    short* Wtlo   = (short*)p;

    hipMemsetAsync(degc, 0, 65536, stream);   // degc + dstc (adjacent)

    hist_kernel<<<N_EDGES / 256, 256, 0, stream>>>(src, dst, degc, dstc);
    dinv_kernel<<<N_NODES / 256, 256, 0, stream>>>(degc, dinv);
    scan_kernel<<<1, 256, 0, stream>>>(dstc, rowptr, cursor);
    fill_kernel<<<N_EDGES / 256, 256, 0, stream>>>(src, dst, cursor, colidx);

    cvtX_kernel<<<(N_NODES * IN_DIM / 4) / 256, 256, 0, stream>>>((const f32x4*)in_feat,
                                                                  (s16x4*)Xhi, (s16x4*)Xlo);
    cvtW_kernel<<<(H_DIM * IN_DIM) / 256, 256, 0, stream>>>(W, Wthi, Wtlo);

    gemm_h_mfma<<<N_NODES / 128, 256, 0, stream>>>(Xhi, Xlo, Wthi, Wtlo, b, dinv, F0, tA);

    prop_kernel<<<N_NODES, 128, 0, stream>>>(F0, tA, F1, tB, dinv, rowptr, colidx);
    prop_kernel<<<N_NODES, 128, 0, stream>>>(F1, tB, F2, tA, dinv, rowptr, colidx);
    prop_kernel<<<N_NODES, 128, 0, stream>>>(F2, tA, F3, tB, dinv, rowptr, colidx);

    acc_kernel<<<(N_NODES * H_DIM / 4) / 256, 256, 0, stream>>>((const f32x4*)F0, (const f32x4*)F1,
                                                                (const f32x4*)F2, (const f32x4*)F3,
                                                                (s16x4*)accb);

    dim3 g(N_NODES / 128, N_NODES / 128, 4);
    out_gemm_kernel<<<g, 256, 0, stream>>>(accb, out);
}